// Round 1
// baseline (801.104 us; speedup 1.0000x reference)
//
#include <hip/hip_runtime.h>
#include <math.h>

#define NA 10000
#define NE 250000
#define FD 128
#define NRBF 20
#define RCUT 5.0f

// ---------------- GEMM: C[M,N] = act(A[M,K] @ B[K,N] + bias) ----------------
// act: 0 = none, 1 = silu
#define TM 64
#define TN 64
#define KT 16
#define SA 68
#define SB 64

__global__ __launch_bounds__(256) void gemm_kernel(
    const float* __restrict__ A, const float* __restrict__ B,
    const float* __restrict__ bias, float* __restrict__ C,
    int M, int N, int K, int act)
{
    __shared__ float As[KT * SA];
    __shared__ float Bs[KT * SB];
    const int tid = threadIdx.x;
    const int tx = tid & 15;        // col group
    const int ty = tid >> 4;        // row group
    const int row0 = blockIdx.y * TM;
    const int col0 = blockIdx.x * TN;

    const int arow = tid >> 2;          // 0..63
    const int acol = (tid & 3) * 4;     // 0,4,8,12
    const int brow = tid >> 4;          // 0..15
    const int bcol = (tid & 15) * 4;    // 0..60

    float acc[4][4] = {};

    for (int k0 = 0; k0 < K; k0 += KT) {
        float4 av = make_float4(0.f, 0.f, 0.f, 0.f);
        if (row0 + arow < M)
            av = *(const float4*)&A[(size_t)(row0 + arow) * K + k0 + acol];
        As[(acol + 0) * SA + arow] = av.x;
        As[(acol + 1) * SA + arow] = av.y;
        As[(acol + 2) * SA + arow] = av.z;
        As[(acol + 3) * SA + arow] = av.w;
        float4 bv = *(const float4*)&B[(size_t)(k0 + brow) * N + col0 + bcol];
        *(float4*)&Bs[brow * SB + bcol] = bv;
        __syncthreads();
#pragma unroll
        for (int k = 0; k < KT; ++k) {
            float4 a = *(const float4*)&As[k * SA + ty * 4];
            float4 b = *(const float4*)&Bs[k * SB + tx * 4];
            float ar[4] = {a.x, a.y, a.z, a.w};
            float br[4] = {b.x, b.y, b.z, b.w};
#pragma unroll
            for (int i = 0; i < 4; ++i)
#pragma unroll
                for (int j = 0; j < 4; ++j)
                    acc[i][j] = fmaf(ar[i], br[j], acc[i][j]);
        }
        __syncthreads();
    }

    float4 bb = make_float4(0.f, 0.f, 0.f, 0.f);
    if (bias) bb = *(const float4*)&bias[col0 + tx * 4];
    float bbr[4] = {bb.x, bb.y, bb.z, bb.w};
#pragma unroll
    for (int i = 0; i < 4; ++i) {
        int row = row0 + ty * 4 + i;
        if (row >= M) continue;
        float4 out;
        float v[4];
#pragma unroll
        for (int j = 0; j < 4; ++j) {
            float t = acc[i][j] + bbr[j];
            if (act == 1) t = t / (1.f + expf(-t));
            v[j] = t;
        }
        out.x = v[0]; out.y = v[1]; out.z = v[2]; out.w = v[3];
        *(float4*)&C[(size_t)row * N + col0 + tx * 4] = out;
    }
}

// ---------------- geometry + RBF record precompute ----------------
// rec[e] = {dir.x, dir.y, dir.z, fcut, pf[20]}  (24 floats = 96 B)
__global__ void geom_kernel(const float* __restrict__ R,
                            const int* __restrict__ idx_i,
                            const int* __restrict__ idx_j,
                            const float* __restrict__ offsets,
                            float* __restrict__ rec)
{
    int e = blockIdx.x * blockDim.x + threadIdx.x;
    if (e >= NE) return;
    int i = idx_i[e], j = idx_j[e];
    float rx = R[j * 3 + 0] - R[i * 3 + 0] + offsets[e * 3 + 0];
    float ry = R[j * 3 + 1] - R[i * 3 + 1] + offsets[e * 3 + 1];
    float rz = R[j * 3 + 2] - R[i * 3 + 2] + offsets[e * 3 + 2];
    float d = sqrtf(rx * rx + ry * ry + rz * rz);
    float inv = 1.f / d;
    float fcut = 0.f;
    if (d < RCUT) fcut = 0.5f * (cosf(d * (3.14159265358979323846f / RCUT)) + 1.f);
    float* rp = rec + (size_t)e * 24;
    rp[0] = rx * inv; rp[1] = ry * inv; rp[2] = rz * inv; rp[3] = fcut;
    const float delta = RCUT / 19.f;
    const float coeff = -0.5f / (delta * delta);
#pragma unroll
    for (int r = 0; r < NRBF; ++r) {
        float dc = d - (float)r * delta;
        rp[4 + r] = expf(coeff * dc * dc) * fcut;
    }
}

// ---------------- CSR row offsets (idx_i is sorted) ----------------
__global__ void csr_kernel(const int* __restrict__ idx_i, int* __restrict__ row_start)
{
    int n = blockIdx.x * blockDim.x + threadIdx.x;
    if (n > NA) return;
    int lo = 0, hi = NE;
    while (lo < hi) {
        int mid = (lo + hi) >> 1;
        if (idx_i[mid] < n) lo = mid + 1; else hi = mid;
    }
    row_start[n] = lo;
}

// ---------------- init: q = emb[Z], mu_ws = 0 ----------------
__global__ __launch_bounds__(128) void init_kernel(const int* __restrict__ Z,
                                                   const float* __restrict__ emb,
                                                   float* __restrict__ q,
                                                   float* __restrict__ mu_ws)
{
    int n = blockIdx.x, f = threadIdx.x;
    q[(size_t)n * FD + f] = emb[(size_t)Z[n] * FD + f];
    float* m = mu_ws + (size_t)n * 384;
    m[f] = 0.f; m[128 + f] = 0.f; m[256 + f] = 0.f;
}

// ---------------- edge message passing (one block per atom, no atomics) ----
__global__ __launch_bounds__(128) void edge_kernel(
    const float* __restrict__ rec, const int* __restrict__ row_start,
    const int* __restrict__ idx_j, const float* __restrict__ x,
    const float* __restrict__ mu_prev, float* __restrict__ mu_next,
    float* __restrict__ q, const float* __restrict__ filt_W,
    const float* __restrict__ filt_b)
{
    const int n = blockIdx.x;
    const int f = threadIdx.x;
    float w0c[NRBF], w1c[NRBF], w2c[NRBF];
#pragma unroll
    for (int r = 0; r < NRBF; ++r) {
        w0c[r] = filt_W[r * 384 + f];
        w1c[r] = filt_W[r * 384 + 128 + f];
        w2c[r] = filt_W[r * 384 + 256 + f];
    }
    const float fb0 = filt_b[f], fb1 = filt_b[128 + f], fb2 = filt_b[256 + f];
    float accq = 0.f, am0 = 0.f, am1 = 0.f, am2 = 0.f;
    const int e0 = row_start[n], e1 = row_start[n + 1];
    for (int e = e0; e < e1; ++e) {
        const float* rp = rec + (size_t)e * 24;
        float4 g = *(const float4*)rp;   // dir, fcut
        float pf[NRBF];
#pragma unroll
        for (int t = 0; t < 5; ++t) {
            float4 p = *(const float4*)(rp + 4 + t * 4);
            pf[t * 4 + 0] = p.x; pf[t * 4 + 1] = p.y;
            pf[t * 4 + 2] = p.z; pf[t * 4 + 3] = p.w;
        }
        int j = idx_j[e];
        float w0 = fb0 * g.w, w1 = fb1 * g.w, w2 = fb2 * g.w;
#pragma unroll
        for (int r = 0; r < NRBF; ++r) {
            w0 = fmaf(pf[r], w0c[r], w0);
            w1 = fmaf(pf[r], w1c[r], w1);
            w2 = fmaf(pf[r], w2c[r], w2);
        }
        const float* xb = x + (size_t)j * 384;
        float xj0 = xb[f], xj1 = xb[128 + f], xj2 = xb[256 + f];
        accq = fmaf(w0, xj0, accq);
        float xw1 = w1 * xj1, xw2 = w2 * xj2;
        const float* mb = mu_prev + (size_t)j * 384;
        am0 += xw1 * g.x + xw2 * mb[f];
        am1 += xw1 * g.y + xw2 * mb[128 + f];
        am2 += xw1 * g.z + xw2 * mb[256 + f];
    }
    q[(size_t)n * FD + f] += accq;
    const float* mp = mu_prev + (size_t)n * 384;
    float* mn = mu_next + (size_t)n * 384;
    mn[f] = mp[f] + am0;
    mn[128 + f] = mp[128 + f] + am1;
    mn[256 + f] = mp[256 + f] + am2;
}

// ---------------- ctx = [q, ||mu_V||] ----------------
__global__ __launch_bounds__(128) void ctx_kernel(const float* __restrict__ q,
                                                  const float* __restrict__ mumix,
                                                  float* __restrict__ ctx)
{
    int n = blockIdx.x, f = threadIdx.x;
    float v0 = mumix[((size_t)n * 3 + 0) * 256 + f];
    float v1 = mumix[((size_t)n * 3 + 1) * 256 + f];
    float v2 = mumix[((size_t)n * 3 + 2) * 256 + f];
    float vn = sqrtf(v0 * v0 + v1 * v1 + v2 * v2 + 1e-8f);
    ctx[(size_t)n * 256 + f] = q[(size_t)n * FD + f];
    ctx[(size_t)n * 256 + 128 + f] = vn;
}

// ---------------- final per-atom mixing update ----------------
__global__ __launch_bounds__(128) void update_kernel(const float* __restrict__ mumix,
                                                     const float* __restrict__ xm,
                                                     float* __restrict__ q,
                                                     float* __restrict__ mu)
{
    int n = blockIdx.x, f = threadIdx.x;
    float v0 = mumix[((size_t)n * 3 + 0) * 256 + f];
    float v1 = mumix[((size_t)n * 3 + 1) * 256 + f];
    float v2 = mumix[((size_t)n * 3 + 2) * 256 + f];
    float w0 = mumix[((size_t)n * 3 + 0) * 256 + 128 + f];
    float w1 = mumix[((size_t)n * 3 + 1) * 256 + 128 + f];
    float w2 = mumix[((size_t)n * 3 + 2) * 256 + 128 + f];
    float sv = v0 * w0 + v1 * w1 + v2 * w2;
    const float* xr = xm + (size_t)n * 384;
    float dq = xr[f], dm = xr[128 + f], dqm = xr[256 + f];
    q[(size_t)n * FD + f] += dq + dqm * sv;
    float* m = mu + (size_t)n * 384;
    m[f] += dm * w0;
    m[128 + f] += dm * w1;
    m[256 + f] += dm * w2;
}

// ---------------- launch ----------------
extern "C" void kernel_launch(void* const* d_in, const int* in_sizes, int n_in,
                              void* d_out, int out_size, void* d_ws, size_t ws_size,
                              hipStream_t stream)
{
    const int*   Z       = (const int*)d_in[0];
    const float* R       = (const float*)d_in[1];
    const int*   idx_i   = (const int*)d_in[2];
    const int*   idx_j   = (const int*)d_in[3];
    const float* offsets = (const float*)d_in[4];
    const float* emb     = (const float*)d_in[5];
    const float* filt_W  = (const float*)d_in[6];
    const float* filt_b  = (const float*)d_in[7];
    const float* int_W1  = (const float*)d_in[8];
    const float* int_b1  = (const float*)d_in[9];
    const float* int_W2  = (const float*)d_in[10];
    const float* int_b2  = (const float*)d_in[11];
    const float* mix_Wmu = (const float*)d_in[12];
    const float* mix_W1  = (const float*)d_in[13];
    const float* mix_b1  = (const float*)d_in[14];
    const float* mix_W2  = (const float*)d_in[15];
    const float* mix_b2  = (const float*)d_in[16];

    float* q_out  = (float*)d_out;                       // [NA,128]
    float* mu_out = (float*)d_out + (size_t)NA * FD;     // [NA,3,128]

    // workspace layout (floats)
    float* ws = (float*)d_ws;
    float* rec    = ws;                                   // NE*24      = 6,000,000
    float* xbuf   = rec + (size_t)NE * 24;                // NA*384     = 3,840,000
    float* hbuf   = xbuf + (size_t)NA * 384;              // NA*128     = 1,280,000
    float* mumix  = hbuf + (size_t)NA * 128;              // NA*3*256   = 7,680,000
    float* mu_ws  = mumix + (size_t)NA * 3 * 256;         // NA*384     = 3,840,000
    int*   row_st = (int*)(mu_ws + (size_t)NA * 384);     // NA+1 ints

    float* ctx = xbuf;   // ctx [NA,256] overlays xbuf (x dead by then; xm written after ctx consumed)

    // setup
    geom_kernel<<<(NE + 255) / 256, 256, 0, stream>>>(R, idx_i, idx_j, offsets, rec);
    csr_kernel<<<(NA + 1 + 255) / 256, 256, 0, stream>>>(idx_i, row_st);
    init_kernel<<<NA, 128, 0, stream>>>(Z, emb, q_out, mu_ws);

    for (int it = 0; it < 3; ++it) {
        const float* W1i  = int_W1 + (size_t)it * 128 * 128;
        const float* b1i  = int_b1 + (size_t)it * 128;
        const float* W2i  = int_W2 + (size_t)it * 128 * 384;
        const float* b2i  = int_b2 + (size_t)it * 384;
        const float* Wmui = mix_Wmu + (size_t)it * 128 * 256;
        const float* mW1  = mix_W1 + (size_t)it * 256 * 128;
        const float* mb1  = mix_b1 + (size_t)it * 128;
        const float* mW2  = mix_W2 + (size_t)it * 128 * 384;
        const float* mb2  = mix_b2 + (size_t)it * 384;

        // mu ping-pong: it0 ws->out, it1 out->ws, it2 ws->out
        float* mu_prev = (it & 1) ? mu_out : mu_ws;
        float* mu_next = (it & 1) ? mu_ws : mu_out;

        // interaction MLP: h = silu(q @ W1 + b1); x = h @ W2 + b2
        gemm_kernel<<<dim3(128 / TN, (NA + TM - 1) / TM), 256, 0, stream>>>(
            q_out, W1i, b1i, hbuf, NA, 128, 128, 1);
        gemm_kernel<<<dim3(384 / TN, (NA + TM - 1) / TM), 256, 0, stream>>>(
            hbuf, W2i, b2i, xbuf, NA, 384, 128, 0);

        // edge messages: q += dq ; mu_next = mu_prev + dmu
        edge_kernel<<<NA, 128, 0, stream>>>(rec, row_st, idx_j, xbuf,
                                            mu_prev, mu_next, q_out, filt_W, filt_b);

        // mixing
        gemm_kernel<<<dim3(256 / TN, (3 * NA + TM - 1) / TM), 256, 0, stream>>>(
            mu_next, Wmui, nullptr, mumix, 3 * NA, 256, 128, 0);
        ctx_kernel<<<NA, 128, 0, stream>>>(q_out, mumix, ctx);
        gemm_kernel<<<dim3(128 / TN, (NA + TM - 1) / TM), 256, 0, stream>>>(
            ctx, mW1, mb1, hbuf, NA, 128, 256, 1);
        gemm_kernel<<<dim3(384 / TN, (NA + TM - 1) / TM), 256, 0, stream>>>(
            hbuf, mW2, mb2, xbuf, NA, 384, 128, 0);
        update_kernel<<<NA, 128, 0, stream>>>(mumix, xbuf, q_out, mu_next);
    }
}

// Round 2
// 595.197 us; speedup vs baseline: 1.3459x; 1.3459x over previous
//
#include <hip/hip_runtime.h>
#include <math.h>

#define NA 10000
#define NE 250000
#define FD 128
#define NRBF 20
#define RCUT 5.0f

typedef __attribute__((ext_vector_type(8))) short short8;
typedef __attribute__((ext_vector_type(4))) float f32x4;

static __device__ __forceinline__ short f2bf(float f) {
    union { float f; unsigned u; } x; x.f = f;
    unsigned r = (x.u + 0x7fffu + ((x.u >> 16) & 1u)) >> 16;
    return (short)r;
}
static __device__ __forceinline__ float bf2f(short s) {
    union { unsigned u; float f; } x; x.u = ((unsigned)(unsigned short)s) << 16;
    return x.f;
}

// ---------------- bf16 MFMA GEMM: C[M,N] = act(A[M,K] @ B[K,N] + bias) -----
// A fp32 (converted in staging), Bt = B^T bf16 [N][K]. act: 0=none, 1=silu.
// Writes Cf (fp32) and/or Cb (bf16), either may be null.
#define LDST 40   // LDS row stride in bf16 elements (80 B -> 2-way bank alias, free)

__global__ __launch_bounds__(256) void gemm_bf16_kernel(
    const float* __restrict__ A, const short* __restrict__ Bt,
    const float* __restrict__ bias, float* __restrict__ Cf, short* __restrict__ Cb,
    int M, int N, int K, int act)
{
    __shared__ short As[64 * LDST];
    __shared__ short Bs[64 * LDST];
    const int tid = threadIdx.x;
    const int wave = tid >> 6;
    const int lane = tid & 63;
    const int row0 = blockIdx.y * 64;
    const int col0 = blockIdx.x * 64;

    const int sr = tid >> 2;         // staging row 0..63
    const int sk = (tid & 3) * 8;    // staging k offset 0,8,16,24

    f32x4 acc[4] = {{0.f,0.f,0.f,0.f},{0.f,0.f,0.f,0.f},{0.f,0.f,0.f,0.f},{0.f,0.f,0.f,0.f}};

    for (int k0 = 0; k0 < K; k0 += 32) {
        // stage A tile [64 rows x 32 k] fp32 -> bf16
        short8 as8;
        int am = row0 + sr;
        if (am < M) {
            const float* ap = A + (size_t)am * K + k0 + sk;
            float4 a0 = *(const float4*)ap;
            float4 a1 = *(const float4*)(ap + 4);
            as8[0] = f2bf(a0.x); as8[1] = f2bf(a0.y); as8[2] = f2bf(a0.z); as8[3] = f2bf(a0.w);
            as8[4] = f2bf(a1.x); as8[5] = f2bf(a1.y); as8[6] = f2bf(a1.z); as8[7] = f2bf(a1.w);
        } else {
#pragma unroll
            for (int i = 0; i < 8; ++i) as8[i] = 0;
        }
        *(short8*)&As[sr * LDST + sk] = as8;
        // stage B^T tile [64 cols x 32 k] (already bf16)
        short8 bs8 = *(const short8*)&Bt[(size_t)(col0 + sr) * K + k0 + sk];
        *(short8*)&Bs[sr * LDST + sk] = bs8;
        __syncthreads();

        // wave computes rows [wave*16, wave*16+16), cols 0..63 (4 tiles)
        short8 afrag = *(const short8*)&As[(wave * 16 + (lane & 15)) * LDST + (lane >> 4) * 8];
#pragma unroll
        for (int t = 0; t < 4; ++t) {
            short8 bfrag = *(const short8*)&Bs[(t * 16 + (lane & 15)) * LDST + (lane >> 4) * 8];
            acc[t] = __builtin_amdgcn_mfma_f32_16x16x32_bf16(afrag, bfrag, acc[t], 0, 0, 0);
        }
        __syncthreads();
    }

#pragma unroll
    for (int t = 0; t < 4; ++t) {
        int col = col0 + t * 16 + (lane & 15);
        float bb = bias ? bias[col] : 0.f;
#pragma unroll
        for (int r = 0; r < 4; ++r) {
            int row = row0 + wave * 16 + (lane >> 4) * 4 + r;
            if (row < M) {
                float v = acc[t][r] + bb;
                if (act) v = v / (1.f + expf(-v));
                if (Cf) Cf[(size_t)row * N + col] = v;
                if (Cb) Cb[(size_t)row * N + col] = f2bf(v);
            }
        }
    }
}

// ---------------- weight transpose+convert: Bt[b][n][k] = W[b][k][n] -------
__global__ void wtrans_kernel(const float* __restrict__ W, short* __restrict__ Bt,
                              int K, int N)
{
    int idx = blockIdx.x * 256 + threadIdx.x;
    int total = K * N;
    if (idx >= total) return;
    int n = idx / K, k = idx - n * K;
    const float* Wb = W + (size_t)blockIdx.y * total;
    short* Bb = Bt + (size_t)blockIdx.y * total;
    Bb[(size_t)n * K + k] = f2bf(Wb[(size_t)k * N + n]);
}

// ---------------- geometry + RBF record precompute ----------------
__global__ void geom_kernel(const float* __restrict__ R,
                            const int* __restrict__ idx_i,
                            const int* __restrict__ idx_j,
                            const float* __restrict__ offsets,
                            float* __restrict__ rec)
{
    int e = blockIdx.x * blockDim.x + threadIdx.x;
    if (e >= NE) return;
    int i = idx_i[e], j = idx_j[e];
    float rx = R[j * 3 + 0] - R[i * 3 + 0] + offsets[e * 3 + 0];
    float ry = R[j * 3 + 1] - R[i * 3 + 1] + offsets[e * 3 + 1];
    float rz = R[j * 3 + 2] - R[i * 3 + 2] + offsets[e * 3 + 2];
    float d = sqrtf(rx * rx + ry * ry + rz * rz);
    float inv = 1.f / d;
    float fcut = 0.f;
    if (d < RCUT) fcut = 0.5f * (cosf(d * (3.14159265358979323846f / RCUT)) + 1.f);
    float* rp = rec + (size_t)e * 24;
    rp[0] = rx * inv; rp[1] = ry * inv; rp[2] = rz * inv; rp[3] = fcut;
    const float delta = RCUT / 19.f;
    const float coeff = -0.5f / (delta * delta);
#pragma unroll
    for (int r = 0; r < NRBF; ++r) {
        float dc = d - (float)r * delta;
        rp[4 + r] = expf(coeff * dc * dc) * fcut;
    }
}

// ---------------- CSR row offsets (idx_i sorted) ----------------
__global__ void csr_kernel(const int* __restrict__ idx_i, int* __restrict__ row_start)
{
    int n = blockIdx.x * blockDim.x + threadIdx.x;
    if (n > NA) return;
    int lo = 0, hi = NE;
    while (lo < hi) {
        int mid = (lo + hi) >> 1;
        if (idx_i[mid] < n) lo = mid + 1; else hi = mid;
    }
    row_start[n] = lo;
}

// ---------------- init: q = emb[Z], mu_ws = 0, mu16 = 0 ----------------
__global__ __launch_bounds__(128) void init_kernel(const int* __restrict__ Z,
                                                   const float* __restrict__ emb,
                                                   float* __restrict__ q,
                                                   float* __restrict__ mu_ws,
                                                   short* __restrict__ mu16)
{
    int n = blockIdx.x, f = threadIdx.x;
    q[(size_t)n * FD + f] = emb[(size_t)Z[n] * FD + f];
    float* m = mu_ws + (size_t)n * 384;
    m[f] = 0.f; m[128 + f] = 0.f; m[256 + f] = 0.f;
    short* m16 = mu16 + (size_t)n * 384;
    m16[f] = 0; m16[128 + f] = 0; m16[256 + f] = 0;
}

// ---------------- edge message passing (one block per atom, no atomics) ----
__global__ __launch_bounds__(128) void edge_kernel(
    const float* __restrict__ rec, const int* __restrict__ row_start,
    const int* __restrict__ idx_j, const short* __restrict__ x16,
    const short* __restrict__ mu16, const float* __restrict__ mu_prev,
    float* __restrict__ mu_next, float* __restrict__ q,
    const float* __restrict__ filt_W, const float* __restrict__ filt_b)
{
    const int n = blockIdx.x;
    const int f = threadIdx.x;
    float w0c[NRBF], w1c[NRBF], w2c[NRBF];
#pragma unroll
    for (int r = 0; r < NRBF; ++r) {
        w0c[r] = filt_W[r * 384 + f];
        w1c[r] = filt_W[r * 384 + 128 + f];
        w2c[r] = filt_W[r * 384 + 256 + f];
    }
    const float fb0 = filt_b[f], fb1 = filt_b[128 + f], fb2 = filt_b[256 + f];
    float accq = 0.f, am0 = 0.f, am1 = 0.f, am2 = 0.f;
    const int e0 = row_start[n], e1 = row_start[n + 1];
    for (int e = e0; e < e1; ++e) {
        const float* rp = rec + (size_t)e * 24;
        float4 g = *(const float4*)rp;   // dir.xyz, fcut
        float pf[NRBF];
#pragma unroll
        for (int t = 0; t < 5; ++t) {
            float4 p = *(const float4*)(rp + 4 + t * 4);
            pf[t * 4 + 0] = p.x; pf[t * 4 + 1] = p.y;
            pf[t * 4 + 2] = p.z; pf[t * 4 + 3] = p.w;
        }
        int j = idx_j[e];
        float w0 = fb0 * g.w, w1 = fb1 * g.w, w2 = fb2 * g.w;
#pragma unroll
        for (int r = 0; r < NRBF; ++r) {
            w0 = fmaf(pf[r], w0c[r], w0);
            w1 = fmaf(pf[r], w1c[r], w1);
            w2 = fmaf(pf[r], w2c[r], w2);
        }
        const short* xb = x16 + (size_t)j * 384;
        float xj0 = bf2f(xb[f]), xj1 = bf2f(xb[128 + f]), xj2 = bf2f(xb[256 + f]);
        accq = fmaf(w0, xj0, accq);
        float xw1 = w1 * xj1, xw2 = w2 * xj2;
        const short* mb = mu16 + (size_t)j * 384;
        am0 += xw1 * g.x + xw2 * bf2f(mb[f]);
        am1 += xw1 * g.y + xw2 * bf2f(mb[128 + f]);
        am2 += xw1 * g.z + xw2 * bf2f(mb[256 + f]);
    }
    q[(size_t)n * FD + f] += accq;
    const float* mp = mu_prev + (size_t)n * 384;
    float* mn = mu_next + (size_t)n * 384;
    mn[f] = mp[f] + am0;
    mn[128 + f] = mp[128 + f] + am1;
    mn[256 + f] = mp[256 + f] + am2;
}

// ---------------- ctx = [q, ||mu_V||] ----------------
__global__ __launch_bounds__(128) void ctx_kernel(const float* __restrict__ q,
                                                  const float* __restrict__ mumix,
                                                  float* __restrict__ ctx)
{
    int n = blockIdx.x, f = threadIdx.x;
    float v0 = mumix[((size_t)n * 3 + 0) * 256 + f];
    float v1 = mumix[((size_t)n * 3 + 1) * 256 + f];
    float v2 = mumix[((size_t)n * 3 + 2) * 256 + f];
    float vn = sqrtf(v0 * v0 + v1 * v1 + v2 * v2 + 1e-8f);
    ctx[(size_t)n * 256 + f] = q[(size_t)n * FD + f];
    ctx[(size_t)n * 256 + 128 + f] = vn;
}

// ---------------- final per-atom mixing update (also writes mu16) ----------
__global__ __launch_bounds__(128) void update_kernel(const float* __restrict__ mumix,
                                                     const float* __restrict__ xm,
                                                     float* __restrict__ q,
                                                     float* __restrict__ mu,
                                                     short* __restrict__ mu16)
{
    int n = blockIdx.x, f = threadIdx.x;
    float v0 = mumix[((size_t)n * 3 + 0) * 256 + f];
    float v1 = mumix[((size_t)n * 3 + 1) * 256 + f];
    float v2 = mumix[((size_t)n * 3 + 2) * 256 + f];
    float w0 = mumix[((size_t)n * 3 + 0) * 256 + 128 + f];
    float w1 = mumix[((size_t)n * 3 + 1) * 256 + 128 + f];
    float w2 = mumix[((size_t)n * 3 + 2) * 256 + 128 + f];
    float sv = v0 * w0 + v1 * w1 + v2 * w2;
    const float* xr = xm + (size_t)n * 384;
    float dq = xr[f], dm = xr[128 + f], dqm = xr[256 + f];
    q[(size_t)n * FD + f] += dq + dqm * sv;
    float* m = mu + (size_t)n * 384;
    float nm0 = m[f] + dm * w0;
    float nm1 = m[128 + f] + dm * w1;
    float nm2 = m[256 + f] + dm * w2;
    m[f] = nm0; m[128 + f] = nm1; m[256 + f] = nm2;
    short* m16 = mu16 + (size_t)n * 384;
    m16[f] = f2bf(nm0); m16[128 + f] = f2bf(nm1); m16[256 + f] = f2bf(nm2);
}

// ---------------- launch ----------------
extern "C" void kernel_launch(void* const* d_in, const int* in_sizes, int n_in,
                              void* d_out, int out_size, void* d_ws, size_t ws_size,
                              hipStream_t stream)
{
    const int*   Z       = (const int*)d_in[0];
    const float* R       = (const float*)d_in[1];
    const int*   idx_i   = (const int*)d_in[2];
    const int*   idx_j   = (const int*)d_in[3];
    const float* offsets = (const float*)d_in[4];
    const float* emb     = (const float*)d_in[5];
    const float* filt_W  = (const float*)d_in[6];
    const float* filt_b  = (const float*)d_in[7];
    const float* int_W1  = (const float*)d_in[8];
    const float* int_b1  = (const float*)d_in[9];
    const float* int_W2  = (const float*)d_in[10];
    const float* int_b2  = (const float*)d_in[11];
    const float* mix_Wmu = (const float*)d_in[12];
    const float* mix_W1  = (const float*)d_in[13];
    const float* mix_b1  = (const float*)d_in[14];
    const float* mix_W2  = (const float*)d_in[15];
    const float* mix_b2  = (const float*)d_in[16];

    float* q_out  = (float*)d_out;                       // [NA,128]
    float* mu_out = (float*)d_out + (size_t)NA * FD;     // [NA,3,128]

    // workspace layout
    float* ws = (float*)d_ws;
    float* rec    = ws;                                   // NE*24
    float* xbuf   = rec + (size_t)NE * 24;                // NA*384 (fp32 xm; ctx overlays)
    float* hbuf   = xbuf + (size_t)NA * 384;              // NA*128
    float* mumix  = hbuf + (size_t)NA * 128;              // NA*3*256
    float* mu_ws  = mumix + (size_t)NA * 3 * 256;         // NA*384
    short* x16    = (short*)(mu_ws + (size_t)NA * 384);   // NA*384 bf16
    short* mu16   = x16 + (size_t)NA * 384;               // NA*384 bf16
    short* bt     = mu16 + (size_t)NA * 384;              // 540672 bf16 weights
    short* bt_W1  = bt;                                   // 3*128*128
    short* bt_W2  = bt_W1 + 3 * 128 * 128;                // 3*384*128
    short* bt_Wmu = bt_W2 + 3 * 384 * 128;                // 3*256*128
    short* bt_mW1 = bt_Wmu + 3 * 256 * 128;               // 3*128*256
    short* bt_mW2 = bt_mW1 + 3 * 128 * 256;               // 3*384*128
    int*   row_st = (int*)(bt_mW2 + 3 * 384 * 128);       // NA+1

    float* ctx = xbuf;  // overlays xbuf: ctx consumed before xm written

    // setup
    geom_kernel<<<(NE + 255) / 256, 256, 0, stream>>>(R, idx_i, idx_j, offsets, rec);
    csr_kernel<<<(NA + 1 + 255) / 256, 256, 0, stream>>>(idx_i, row_st);
    init_kernel<<<NA, 128, 0, stream>>>(Z, emb, q_out, mu_ws, mu16);
    wtrans_kernel<<<dim3((128 * 128 + 255) / 256, 3), 256, 0, stream>>>(int_W1, bt_W1, 128, 128);
    wtrans_kernel<<<dim3((128 * 384 + 255) / 256, 3), 256, 0, stream>>>(int_W2, bt_W2, 128, 384);
    wtrans_kernel<<<dim3((128 * 256 + 255) / 256, 3), 256, 0, stream>>>(mix_Wmu, bt_Wmu, 128, 256);
    wtrans_kernel<<<dim3((256 * 128 + 255) / 256, 3), 256, 0, stream>>>(mix_W1, bt_mW1, 256, 128);
    wtrans_kernel<<<dim3((128 * 384 + 255) / 256, 3), 256, 0, stream>>>(mix_W2, bt_mW2, 128, 384);

    for (int it = 0; it < 3; ++it) {
        const short* W1i  = bt_W1 + (size_t)it * 128 * 128;
        const float* b1i  = int_b1 + (size_t)it * 128;
        const short* W2i  = bt_W2 + (size_t)it * 384 * 128;
        const float* b2i  = int_b2 + (size_t)it * 384;
        const short* Wmui = bt_Wmu + (size_t)it * 256 * 128;
        const short* mW1  = bt_mW1 + (size_t)it * 128 * 256;
        const float* mb1  = mix_b1 + (size_t)it * 128;
        const short* mW2  = bt_mW2 + (size_t)it * 384 * 128;
        const float* mb2  = mix_b2 + (size_t)it * 384;

        float* mu_prev = (it & 1) ? mu_out : mu_ws;
        float* mu_next = (it & 1) ? mu_ws : mu_out;

        // interaction MLP: h = silu(q @ W1 + b1); x16 = bf16(h @ W2 + b2)
        gemm_bf16_kernel<<<dim3(2, (NA + 63) / 64), 256, 0, stream>>>(
            q_out, W1i, b1i, hbuf, nullptr, NA, 128, 128, 1);
        gemm_bf16_kernel<<<dim3(6, (NA + 63) / 64), 256, 0, stream>>>(
            hbuf, W2i, b2i, nullptr, x16, NA, 384, 128, 0);

        // edge messages
        edge_kernel<<<NA, 128, 0, stream>>>(rec, row_st, idx_j, x16, mu16,
                                            mu_prev, mu_next, q_out, filt_W, filt_b);

        // mixing
        gemm_bf16_kernel<<<dim3(4, (3 * NA + 63) / 64), 256, 0, stream>>>(
            mu_next, Wmui, nullptr, mumix, nullptr, 3 * NA, 256, 128, 0);
        ctx_kernel<<<NA, 128, 0, stream>>>(q_out, mumix, ctx);
        gemm_bf16_kernel<<<dim3(2, (NA + 63) / 64), 256, 0, stream>>>(
            ctx, mW1, mb1, hbuf, nullptr, NA, 128, 256, 1);
        gemm_bf16_kernel<<<dim3(6, (NA + 63) / 64), 256, 0, stream>>>(
            hbuf, mW2, mb2, xbuf, nullptr, NA, 384, 128, 0);
        update_kernel<<<NA, 128, 0, stream>>>(mumix, xbuf, q_out, mu_next, mu16);
    }
}